// Round 8
// baseline (525.755 us; speedup 1.0000x reference)
//
#include <hip/hip_runtime.h>
#include <hip/hip_cooperative_groups.h>

namespace cg = cooperative_groups;

#define D 128
#define RS_STRIDE 64      // floats (256 B) between result slots

typedef __attribute__((ext_vector_type(8))) short bf16x8;
typedef __attribute__((ext_vector_type(8))) unsigned short u16x8;
typedef __attribute__((ext_vector_type(4))) float f32x4;

struct KParams {
    const int* node_ids; const int* nbr; const int* seg;
    const float* W; const float* M; const float* emb;
    unsigned short* embb; unsigned short* Wb; unsigned short* Mb;
    unsigned short* aggb; float* rs; int* row_ptr; float* out;
    int n4; int E; int N; int njobs;
};

__device__ __forceinline__ unsigned short f2bf(float f) {
    unsigned u = __float_as_uint(f);
    unsigned r = (u + 0x7fffu + ((u >> 16) & 1u)) >> 16;
    return (unsigned short)r;
}
__device__ __forceinline__ float bf2f(unsigned short h) {
    return __uint_as_float(((unsigned)h) << 16);
}
__device__ __forceinline__ ushort4 pack4(float4 v) {
    ushort4 o; o.x = f2bf(v.x); o.y = f2bf(v.y); o.z = f2bf(v.z); o.w = f2bf(v.w);
    return o;
}

// ---- phase 1: emb/W/M -> bf16, zero rs, row_ptr from sorted seg -----------
__device__ __forceinline__ void prep_work(const KParams& p, int gtid, int T) {
    for (int i = gtid; i < p.n4; i += T)
        ((ushort4*)p.embb)[i] = pack4(((const float4*)p.emb)[i]);
    if (gtid < 4096)      ((ushort4*)p.Wb)[gtid]        = pack4(((const float4*)p.W)[gtid]);
    else if (gtid < 8192) ((ushort4*)p.Mb)[gtid - 4096] = pack4(((const float4*)p.M)[gtid - 4096]);
    if (gtid < D) p.rs[gtid * RS_STRIDE] = 0.0f;
    for (int i = gtid; i < p.E; i += T) {
        int s = p.seg[i];
        if (i == 0) {
            for (int n = 0; n <= s; ++n) p.row_ptr[n] = 0;
        } else {
            int sp = p.seg[i - 1];
            for (int n = sp + 1; n <= s; ++n) p.row_ptr[n] = i;
        }
        if (i == p.E - 1) {
            for (int n = s + 1; n <= p.N; ++n) p.row_ptr[n] = p.E;
        }
    }
}

// ---- phase 2: segment-sum bf16 rows -> bf16 aggb (R4-proven shape) --------
// 64 lanes/node: 8 edge streams (j) x 8 chunk-lanes (c, chunks c and c+8),
// next-id software prefetch, fp32 accumulate.
__device__ __forceinline__ void agg_node(const int* __restrict__ nbr,
                                         const int* __restrict__ row_ptr,
                                         const unsigned short* __restrict__ embb,
                                         unsigned short* __restrict__ aggb,
                                         int n, int tt) {
    int c = tt & 7;
    int j = tt >> 3;
    int lo = row_ptr[n], hi = row_ptr[n + 1];

    float s0[8], s1[8];
#pragma unroll
    for (int k = 0; k < 8; ++k) { s0[k] = 0.f; s1[k] = 0.f; }

    int e = lo + j;
    int id = (e < hi) ? nbr[e] : -1;
    while (id >= 0) {
        const u16x8* r = (const u16x8*)(embb + (size_t)id * D);
        int e2 = e + 8;
        int id2 = (e2 < hi) ? nbr[e2] : -1;   // prefetch next id
        u16x8 v0 = r[c], v1 = r[c + 8];
#pragma unroll
        for (int k = 0; k < 8; ++k) {
            s0[k] += bf2f((unsigned short)v0[k]);
            s1[k] += bf2f((unsigned short)v1[k]);
        }
        e = e2; id = id2;
    }
#pragma unroll
    for (int k = 0; k < 8; ++k) {
        float x = s0[k], y = s1[k];
        x += __shfl_xor(x, 8);  y += __shfl_xor(y, 8);
        x += __shfl_xor(x, 16); y += __shfl_xor(y, 16);
        x += __shfl_xor(x, 32); y += __shfl_xor(y, 32);
        s0[k] = x; s1[k] = y;
    }
    if (j == 0) {
        u16x8 o0, o1;
#pragma unroll
        for (int k = 0; k < 8; ++k) { o0[k] = f2bf(s0[k]); o1[k] = f2bf(s1[k]); }
        u16x8* o = (u16x8*)(aggb + (size_t)n * D);
        o[c] = o0;
        o[c + 8] = o1;
    }
}

// ---- phase 3: MFMA matvec + relu + column-sum, job = (dim-tile, 16-node grp)
// A-frag: A[m=lane&15][k=quad*8+j]; B-frag: B[k=quad*8+j][n=lane&15] = W[n][k]
// C/D: col=lane&15 (dim), row=quad*4+reg (node).
__device__ __forceinline__ void mv_job(const KParams& p, int dt, int grp, int l) {
    int quad = l >> 4, col = l & 15;
    const bf16x8 zero8 = {0, 0, 0, 0, 0, 0, 0, 0};

    int node = grp * 16 + col;
    bool valid = node < p.N;
    int nid = valid ? p.node_ids[node] : 0;
    const unsigned short* xr = p.embb + (size_t)nid * D + quad * 8;
    const unsigned short* ar = p.aggb + (size_t)node * D + quad * 8;
    int wrow = (dt * 16 + col) * D + quad * 8;

    f32x4 acc = {0.f, 0.f, 0.f, 0.f};
#pragma unroll
    for (int ks = 0; ks < 4; ++ks) {
        bf16x8 bw = *(const bf16x8*)(p.Wb + wrow + ks * 32);
        bf16x8 bm = *(const bf16x8*)(p.Mb + wrow + ks * 32);
        bf16x8 ax = valid ? *(const bf16x8*)(xr + ks * 32) : zero8;
        bf16x8 aa = valid ? *(const bf16x8*)(ar + ks * 32) : zero8;
        acc = __builtin_amdgcn_mfma_f32_16x16x32_bf16(ax, bw, acc, 0, 0, 0);
        acc = __builtin_amdgcn_mfma_f32_16x16x32_bf16(aa, bm, acc, 0, 0, 0);
    }
    float v = fmaxf(acc[0], 0.f) + fmaxf(acc[1], 0.f)
            + fmaxf(acc[2], 0.f) + fmaxf(acc[3], 0.f);
    v += __shfl_xor(v, 16);
    v += __shfl_xor(v, 32);
    if (l < 16) atomicAdd(&p.rs[(dt * 16 + col) * RS_STRIDE], v);
}

// ---- phase 4: softmax over the 128 strided slots --------------------------
__device__ __forceinline__ void softmax_work(const KParams& p, int t) {
    float v0 = __hip_atomic_load(&p.rs[t * RS_STRIDE],
                                 __ATOMIC_RELAXED, __HIP_MEMORY_SCOPE_AGENT);
    float v1 = __hip_atomic_load(&p.rs[(t + 64) * RS_STRIDE],
                                 __ATOMIC_RELAXED, __HIP_MEMORY_SCOPE_AGENT);
    float m = fmaxf(v0, v1);
    for (int o = 32; o > 0; o >>= 1) m = fmaxf(m, __shfl_xor(m, o));
    float e0 = expf(v0 - m);
    float e1 = expf(v1 - m);
    float s = e0 + e1;
    for (int o = 32; o > 0; o >>= 1) s += __shfl_xor(s, o);
    float inv = 1.0f / s;
    p.out[t] = e0 * inv;
    p.out[t + 64] = e1 * inv;
}

// -------------------------------------------------------------------------
// Single cooperative kernel: prep | agg | matvec | softmax with grid.sync().
__global__ __launch_bounds__(256) void mega_kernel(KParams p) {
    cg::grid_group grid = cg::this_grid();
    int t = threadIdx.x;
    int gtid = blockIdx.x * 256 + t;
    int T = gridDim.x * 256;

    prep_work(p, gtid, T);
    grid.sync();

    int nbagg = (p.N + 3) / 4;
    for (int b = blockIdx.x; b < nbagg; b += gridDim.x) {
        int n = b * 4 + (t >> 6);
        if (n < p.N) agg_node(p.nbr, p.row_ptr, p.embb, p.aggb, n, t & 63);
    }
    grid.sync();

    int gw = gtid >> 6, nw = T >> 6, l = t & 63;
    for (int job = gw; job < p.njobs; job += nw)
        mv_job(p, job & 7, job >> 3, l);
    grid.sync();

    if (blockIdx.x == 0 && t < 64) softmax_work(p, t);
}

// ---- fallback: same device functions as 4 plain kernels -------------------
__global__ __launch_bounds__(256) void prep_kernel(KParams p) {
    prep_work(p, blockIdx.x * 256 + threadIdx.x, gridDim.x * 256);
}
__global__ __launch_bounds__(256) void agg_kernel(KParams p) {
    int nbagg = (p.N + 3) / 4;
    for (int b = blockIdx.x; b < nbagg; b += gridDim.x) {
        int n = b * 4 + (int)(threadIdx.x >> 6);
        if (n < p.N) agg_node(p.nbr, p.row_ptr, p.embb, p.aggb, n, threadIdx.x & 63);
    }
}
__global__ __launch_bounds__(256) void mv_kernel(KParams p) {
    int gtid = blockIdx.x * 256 + threadIdx.x;
    int gw = gtid >> 6, nw = (gridDim.x * 256) >> 6, l = threadIdx.x & 63;
    for (int job = gw; job < p.njobs; job += nw)
        mv_job(p, job & 7, job >> 3, l);
}
__global__ void smax_kernel(KParams p) {
    if (threadIdx.x < 64) softmax_work(p, threadIdx.x);
}

extern "C" void kernel_launch(void* const* d_in, const int* in_sizes, int n_in,
                              void* d_out, int out_size, void* d_ws, size_t ws_size,
                              hipStream_t stream) {
    KParams p;
    p.node_ids = (const int*)d_in[0];
    p.nbr      = (const int*)d_in[1];
    p.seg      = (const int*)d_in[2];
    p.W        = (const float*)d_in[3];
    p.M        = (const float*)d_in[4];
    p.emb      = (const float*)d_in[5];
    p.out      = (float*)d_out;

    p.N = in_sizes[0];
    p.E = in_sizes[1];
    long long VD = in_sizes[5];          // V*D elements
    p.n4 = (int)(VD / 4);
    int ngroups = (p.N + 15) / 16;
    p.njobs = 8 * ngroups;

    // ws layout: embb[V*D] u16 | Wb | Mb u16 | aggb[N*D] u16 | rs f32 | row_ptr
    p.embb    = (unsigned short*)d_ws;
    p.Wb      = p.embb + (size_t)VD;
    p.Mb      = p.Wb + D * D;
    p.aggb    = p.Mb + D * D;
    p.rs      = (float*)(p.aggb + (size_t)p.N * D);
    p.row_ptr = (int*)(p.rs + (size_t)D * RS_STRIDE);

    void* args[] = {&p};
    hipError_t err = hipLaunchCooperativeKernel((const void*)mega_kernel,
                                                dim3(1024), dim3(256), args, 0, stream);
    if (err != hipSuccess) {
        // fallback: plain 4-kernel pipeline (identical math)
        prep_kernel<<<1024, 256, 0, stream>>>(p);
        agg_kernel<<<(p.N + 3) / 4, 256, 0, stream>>>(p);
        mv_kernel<<<(p.njobs + 3) / 4, 256, 0, stream>>>(p);
        smax_kernel<<<1, 64, 0, stream>>>(p);
    }
}

// Round 9
// 226.587 us; speedup vs baseline: 2.3203x; 2.3203x over previous
//
#include <hip/hip_runtime.h>

#define D 128
#define RS_STRIDE 64      // floats (256 B) between result slots

typedef __attribute__((ext_vector_type(8))) short bf16x8;
typedef __attribute__((ext_vector_type(8))) unsigned short u16x8;
typedef __attribute__((ext_vector_type(4))) float f32x4;

__device__ __forceinline__ unsigned short f2bf(float f) {
    unsigned u = __float_as_uint(f);
    unsigned r = (u + 0x7fffu + ((u >> 16) & 1u)) >> 16;
    return (unsigned short)r;
}
__device__ __forceinline__ float bf2f(unsigned short h) {
    return __uint_as_float(((unsigned)h) << 16);
}
__device__ __forceinline__ ushort4 pack4(float4 v) {
    ushort4 o; o.x = f2bf(v.x); o.y = f2bf(v.y); o.z = f2bf(v.z); o.w = f2bf(v.w);
    return o;
}

// -------------------------------------------------------------------------
// One prep pass (R4 convert + R5 fold): emb fp32->bf16, W/M fp32->bf16,
// zero strided rs slots + done counter, row_ptr[N+1] from sorted seg.
__global__ void prep_kernel(const float* __restrict__ emb, const float* __restrict__ W,
                            const float* __restrict__ M, const int* __restrict__ seg,
                            unsigned short* __restrict__ embb, unsigned short* __restrict__ Wb,
                            unsigned short* __restrict__ Mb, float* __restrict__ rs,
                            int* __restrict__ row_ptr, int* __restrict__ done,
                            int n4, int E, int N) {
    int i = blockIdx.x * blockDim.x + threadIdx.x;
    if (i < n4) ((ushort4*)embb)[i] = pack4(((const float4*)emb)[i]);
    if (i < 4096)       ((ushort4*)Wb)[i]        = pack4(((const float4*)W)[i]);
    else if (i < 8192)  ((ushort4*)Mb)[i - 4096] = pack4(((const float4*)M)[i - 4096]);
    if (i < D) rs[i * RS_STRIDE] = 0.0f;
    if (i == D) *done = 0;
    if (i < E) {
        int s = seg[i];
        if (i == 0) {
            for (int n = 0; n <= s; ++n) row_ptr[n] = 0;
        } else {
            int sp = seg[i - 1];
            for (int n = sp + 1; n <= s; ++n) row_ptr[n] = i;
        }
        if (i == E - 1) {
            for (int n = s + 1; n <= N; ++n) row_ptr[n] = E;
        }
    }
}

// -------------------------------------------------------------------------
// R4's exact agg shape (the measured-best): block = 4 nodes; per node 8 edge
// streams x 8 chunk-lanes; lane owns u16x8 chunks (c, c+8); fp32 accum.
__global__ void agg_kernel(const int* __restrict__ nbr, const int* __restrict__ row_ptr,
                           const unsigned short* __restrict__ embb,
                           unsigned short* __restrict__ aggb, int N) {
    int n = blockIdx.x * 4 + (threadIdx.x >> 6);
    if (n >= N) return;
    int tt = threadIdx.x & 63;
    int c = tt & 7;       // chunk
    int j = tt >> 3;      // edge stream 0..7

    int lo = row_ptr[n], hi = row_ptr[n + 1];

    float s0[8], s1[8];
#pragma unroll
    for (int k = 0; k < 8; ++k) { s0[k] = 0.f; s1[k] = 0.f; }

    for (int e = lo + j; e < hi; e += 8) {
        const u16x8* r = (const u16x8*)(embb + (size_t)nbr[e] * D);
        u16x8 v0 = r[c];
        u16x8 v1 = r[c + 8];
#pragma unroll
        for (int k = 0; k < 8; ++k) {
            s0[k] += bf2f((unsigned short)v0[k]);
            s1[k] += bf2f((unsigned short)v1[k]);
        }
    }
#pragma unroll
    for (int k = 0; k < 8; ++k) {
        float x = s0[k], y = s1[k];
        x += __shfl_xor(x, 8);  y += __shfl_xor(y, 8);
        x += __shfl_xor(x, 16); y += __shfl_xor(y, 16);
        x += __shfl_xor(x, 32); y += __shfl_xor(y, 32);
        s0[k] = x; s1[k] = y;
    }

    if (j == 0) {
        u16x8 o0, o1;
#pragma unroll
        for (int k = 0; k < 8; ++k) { o0[k] = f2bf(s0[k]); o1[k] = f2bf(s1[k]); }
        u16x8* o = (u16x8*)(aggb + (size_t)n * D);
        o[c] = o0;
        o[c + 8] = o1;
    }
}

// -------------------------------------------------------------------------
// R4's exact MFMA matvec + fused last-block softmax (R6-proven mechanism).
// Wave job = (dim-tile dt, node stripe); each wave handles 2 16-node groups.
// A-frag: A[m=lane&15][k=quad*8+j]; B-frag: B[k=quad*8+j][n=lane&15] = W[n][k]
// C/D: col=lane&15 (dim), row=quad*4+reg (node).
__global__ __launch_bounds__(256) void matvec_kernel(
    const int* __restrict__ node_ids, const unsigned short* __restrict__ embb,
    const unsigned short* __restrict__ aggb,
    const unsigned short* __restrict__ Wb, const unsigned short* __restrict__ Mb,
    float* __restrict__ rs, int* __restrict__ done, float* __restrict__ out,
    int N, int ngroups, int nstripes, int nblocks) {
    __shared__ int amlast;
    int t = threadIdx.x;
    int wid = blockIdx.x * 4 + (t >> 6);
    int l = t & 63;
    int quad = l >> 4, col = l & 15;
    int dt = wid & 7;
    int stripe = wid >> 3;

    bf16x8 bw[4], bm[4];
    int wrow = (dt * 16 + col) * D;
#pragma unroll
    for (int ks = 0; ks < 4; ++ks) {
        int off = wrow + ks * 32 + quad * 8;
        bw[ks] = *(const bf16x8*)(Wb + off);
        bm[ks] = *(const bf16x8*)(Mb + off);
    }

    const bf16x8 zero8 = {0, 0, 0, 0, 0, 0, 0, 0};
    float vsum = 0.f;

    for (int grp = stripe; grp < ngroups; grp += nstripes) {
        int node = grp * 16 + col;
        bool valid = node < N;
        int nid = valid ? node_ids[node] : 0;
        const unsigned short* xr = embb + (size_t)nid * D + quad * 8;
        const unsigned short* ar = aggb + (size_t)node * D + quad * 8;

        f32x4 acc = {0.f, 0.f, 0.f, 0.f};
#pragma unroll
        for (int ks = 0; ks < 4; ++ks) {
            bf16x8 ax = valid ? *(const bf16x8*)(xr + ks * 32) : zero8;
            bf16x8 aa = valid ? *(const bf16x8*)(ar + ks * 32) : zero8;
            acc = __builtin_amdgcn_mfma_f32_16x16x32_bf16(ax, bw[ks], acc, 0, 0, 0);
            acc = __builtin_amdgcn_mfma_f32_16x16x32_bf16(aa, bm[ks], acc, 0, 0, 0);
        }
        vsum += fmaxf(acc[0], 0.f) + fmaxf(acc[1], 0.f)
              + fmaxf(acc[2], 0.f) + fmaxf(acc[3], 0.f);
    }

    vsum += __shfl_xor(vsum, 16);
    vsum += __shfl_xor(vsum, 32);
    if (l < 16) atomicAdd(&rs[(dt * 16 + col) * RS_STRIDE], vsum);

    // ---- last block finalizes softmax (R6-proven) ----
    __threadfence();
    if (t == 0) amlast = (atomicAdd(done, 1) == nblocks - 1);
    __syncthreads();
    if (amlast && t < 64) {
        __threadfence();
        float v0 = __hip_atomic_load(&rs[t * RS_STRIDE],
                                     __ATOMIC_RELAXED, __HIP_MEMORY_SCOPE_AGENT);
        float v1 = __hip_atomic_load(&rs[(t + 64) * RS_STRIDE],
                                     __ATOMIC_RELAXED, __HIP_MEMORY_SCOPE_AGENT);
        float m = fmaxf(v0, v1);
        for (int o = 32; o > 0; o >>= 1) m = fmaxf(m, __shfl_xor(m, o));
        float e0 = expf(v0 - m);
        float e1 = expf(v1 - m);
        float su = e0 + e1;
        for (int o = 32; o > 0; o >>= 1) su += __shfl_xor(su, o);
        float inv = 1.0f / su;
        out[t] = e0 * inv;
        out[t + 64] = e1 * inv;
    }
}

extern "C" void kernel_launch(void* const* d_in, const int* in_sizes, int n_in,
                              void* d_out, int out_size, void* d_ws, size_t ws_size,
                              hipStream_t stream) {
    const int*   node_ids = (const int*)d_in[0];
    const int*   nbr      = (const int*)d_in[1];
    const int*   seg      = (const int*)d_in[2];
    const float* W        = (const float*)d_in[3];
    const float* M        = (const float*)d_in[4];
    const float* emb      = (const float*)d_in[5];
    float* out = (float*)d_out;

    int N = in_sizes[0];
    int E = in_sizes[1];
    long long VD = in_sizes[5];          // V*D elements
    int ngroups  = (N + 15) / 16;
    int nstripes = (ngroups + 1) / 2;    // each wave: exactly 2 groups
    int mv_blocks = 2 * nstripes;        // 8*nstripes waves / 4 waves-per-block

    // ws layout: embb[V*D] u16 | Wb | Mb u16 | aggb[N*D] u16 | rs f32 |
    //            row_ptr int[N+1] | done
    unsigned short* embb = (unsigned short*)d_ws;
    unsigned short* Wb   = embb + (size_t)VD;
    unsigned short* Mb   = Wb + D * D;
    unsigned short* aggb = Mb + D * D;
    float* rs            = (float*)(aggb + (size_t)N * D);
    int* row_ptr         = (int*)(rs + (size_t)D * RS_STRIDE);
    int* done            = row_ptr + (N + 1);

    int n4 = (int)(VD / 4);
    int prep_n = n4;
    if (prep_n < E) prep_n = E;
    if (prep_n < 8192) prep_n = 8192;

    prep_kernel<<<(prep_n + 255) / 256, 256, 0, stream>>>(emb, W, M, seg, embb, Wb, Mb,
                                                          rs, row_ptr, done, n4, E, N);
    agg_kernel<<<(N + 3) / 4, 256, 0, stream>>>(nbr, row_ptr, embb, aggb, N);
    matvec_kernel<<<mv_blocks, 256, 0, stream>>>(node_ids, embb, aggb, Wb, Mb,
                                                 rs, done, out, N, ngroups, nstripes,
                                                 mv_blocks);
}